// Round 1
// baseline (25.301 us; speedup 1.0000x reference)
//
#include <hip/hip_runtime.h>
#include <math.h>

#define CTX 24
#define DKK 92
#define ED 36
#define NTOK 500
#define HID 152
#define CDIM 936  // 72 + 864

// ---------------------------------------------------------------------------
// Kernel A: both self-attentions. grid=2 blocks (block b = attention b+1),
// 256 threads each. Writes t3 (36) to t_out[0..35], t13 to t_out[36..71].
//
// Math: t[e] = sum_f softmax_col(S)[e,f] * vsum[f]
//   S = sqrt(92) * x0 @ (wq @ wk^T) @ x0^T
//   vsum = x0 @ rowsum(wv)
// ---------------------------------------------------------------------------
__global__ __launch_bounds__(256) void attn_kernel(
    const float* __restrict__ x0,
    const float* __restrict__ wq1, const float* __restrict__ wk1, const float* __restrict__ wv1,
    const float* __restrict__ wq2, const float* __restrict__ wk2, const float* __restrict__ wv2,
    float* __restrict__ t_out)
{
    const float* wq = blockIdx.x ? wq2 : wq1;
    const float* wk = blockIdx.x ? wk2 : wk1;
    const float* wv = blockIdx.x ? wv2 : wv1;
    float* dst = t_out + blockIdx.x * ED;

    __shared__ float x0s[ED * CTX];     // 864
    __shared__ float wqs[CTX * DKK];    // 2208
    __shared__ float wks[CTX * DKK];    // 2208
    __shared__ float W[CTX * CTX];      // 576  (wq @ wk^T)
    __shared__ float M[ED * CTX];       // 864  (x0 @ W)
    __shared__ float S[ED * ED];        // 1296 (scores, then exp(scores-max))
    __shared__ float wvsum[CTX];        // rowsum(wv)
    __shared__ float vs2[ED];           // vsum[f] / colsum[f]

    const int tid = threadIdx.x;

    for (int i = tid; i < ED * CTX; i += 256) x0s[i] = x0[i];
    for (int i = tid; i < CTX * DKK; i += 256) { wqs[i] = wq[i]; wks[i] = wk[i]; }
    if (tid < CTX) {
        float s = 0.f;
        for (int d = 0; d < DKK; ++d) s += wv[tid * DKK + d];
        wvsum[tid] = s;
    }
    __syncthreads();

    // W[a][b] = sum_d wq[a][d] * wk[b][d]   (576 entries, len-92 dots)
    for (int i = tid; i < CTX * CTX; i += 256) {
        const int a = i / CTX, b = i % CTX;
        const float* qa = &wqs[a * DKK];
        const float* kb = &wks[b * DKK];
        float s = 0.f;
        for (int d = 0; d < DKK; ++d) s += qa[d] * kb[d];
        W[i] = s;
    }
    __syncthreads();

    // M[e][b] = sum_a x0[e][a] * W[a][b]
    for (int i = tid; i < ED * CTX; i += 256) {
        const int e = i / CTX, b = i % CTX;
        float s = 0.f;
        for (int a = 0; a < CTX; ++a) s += x0s[e * CTX + a] * W[a * CTX + b];
        M[i] = s;
    }
    __syncthreads();

    // S[e][f] = sqrt(92) * sum_b M[e][b] * x0[f][b]
    const float scale = sqrtf((float)DKK);
    for (int i = tid; i < ED * ED; i += 256) {
        const int e = i / ED, f = i % ED;
        float s = 0.f;
        for (int b = 0; b < CTX; ++b) s += M[e * CTX + b] * x0s[f * CTX + b];
        S[i] = s * scale;
    }
    __syncthreads();

    // Column-wise softmax prep: thread f owns column f.
    // Overwrite S with exp(S - colmax); vs2[f] = vsum[f] / colsum[f].
    if (tid < ED) {
        const int f = tid;
        float mx = -1e30f;
        for (int e = 0; e < ED; ++e) mx = fmaxf(mx, S[e * ED + f]);
        float sum = 0.f;
        for (int e = 0; e < ED; ++e) {
            const float p = expf(S[e * ED + f] - mx);
            S[e * ED + f] = p;
            sum += p;
        }
        float vsum = 0.f;
        for (int c = 0; c < CTX; ++c) vsum += x0s[f * CTX + c] * wvsum[c];
        vs2[f] = vsum / sum;
    }
    __syncthreads();

    // t[e] = sum_f P[e][f] * vs2[f]
    if (tid < ED) {
        const int e = tid;
        float s = 0.f;
        for (int f = 0; f < ED; ++f) s += S[e * ED + f] * vs2[f];
        dst[e] = s;
    }
}

// ---------------------------------------------------------------------------
// Kernel B: h[j] = relu(sum_i t71[i] * nl0[i][j]) + nl0_bias[j], j < 152.
// grid = 19 blocks x 256 threads; block owns 8 columns; threads = 32 i-slices
// x 8 columns; LDS tree-reduce the 32 partials.
// t71 = [t3(36) | t13(36) | x0(864)] ; first 72 read from ws.
// ---------------------------------------------------------------------------
#define JCHUNK 8
__global__ __launch_bounds__(256) void hidden_kernel(
    const float* __restrict__ x0, const float* __restrict__ nl0,
    const float* __restrict__ nl0_bias, const float* __restrict__ t36,
    float* __restrict__ h)
{
    __shared__ float t71[CDIM];
    __shared__ float part[32][JCHUNK];

    const int tid = threadIdx.x;
    for (int i = tid; i < 72; i += 256) t71[i] = t36[i];
    for (int i = tid; i < ED * CTX; i += 256) t71[72 + i] = x0[i];
    __syncthreads();

    const int isub = tid / JCHUNK;   // 0..31
    const int jj   = tid % JCHUNK;   // 0..7
    const int j    = blockIdx.x * JCHUNK + jj;

    float s = 0.f;
    for (int i = isub; i < CDIM; i += 32) s += t71[i] * nl0[i * HID + j];
    part[isub][jj] = s;
    __syncthreads();

    if (tid < JCHUNK) {
        float acc = 0.f;
        for (int k = 0; k < 32; ++k) acc += part[k][tid];
        const int jcol = blockIdx.x * JCHUNK + tid;
        h[jcol] = fmaxf(acc, 0.f) + nl0_bias[jcol];
    }
}

// ---------------------------------------------------------------------------
// Kernel C: t10 = h @ nl1 (36), out = t10 @ ctp + ctp_bias (500).
// 1 block x 512 threads; ctp column reads are lane-coalesced.
// ---------------------------------------------------------------------------
__global__ __launch_bounds__(512) void out_kernel(
    const float* __restrict__ h, const float* __restrict__ nl1,
    const float* __restrict__ ctp, const float* __restrict__ ctp_bias,
    float* __restrict__ out)
{
    __shared__ float hs[HID];
    __shared__ float t10[ED];

    const int tid = threadIdx.x;
    if (tid < HID) hs[tid] = h[tid];
    __syncthreads();

    if (tid < ED) {
        float s = 0.f;
        for (int j = 0; j < HID; ++j) s += hs[j] * nl1[j * ED + tid];
        t10[tid] = s;
    }
    __syncthreads();

    if (tid < NTOK) {
        float s = ctp_bias[tid];
        for (int e = 0; e < ED; ++e) s += t10[e] * ctp[e * NTOK + tid];
        out[tid] = s;
    }
}

extern "C" void kernel_launch(void* const* d_in, const int* in_sizes, int n_in,
                              void* d_out, int out_size, void* d_ws, size_t ws_size,
                              hipStream_t stream) {
    const float* x0       = (const float*)d_in[0];
    const float* wq1      = (const float*)d_in[1];
    const float* wk1      = (const float*)d_in[2];
    const float* wv1      = (const float*)d_in[3];
    const float* wq2      = (const float*)d_in[4];
    const float* wk2      = (const float*)d_in[5];
    const float* wv2      = (const float*)d_in[6];
    const float* nl0      = (const float*)d_in[7];
    const float* nl0_bias = (const float*)d_in[8];
    const float* nl1      = (const float*)d_in[9];
    const float* ctp      = (const float*)d_in[10];
    const float* ctp_bias = (const float*)d_in[11];

    float* ws = (float*)d_ws;   // [0..35]=t3, [36..71]=t13, [72..223]=h

    attn_kernel<<<2, 256, 0, stream>>>(x0, wq1, wk1, wv1, wq2, wk2, wv2, ws);
    hidden_kernel<<<19, 256, 0, stream>>>(x0, nl0, nl0_bias, ws, ws + 72);
    out_kernel<<<1, 512, 0, stream>>>(ws + 72, nl1, ctp, ctp_bias, (float*)d_out);
}